// Round 1
// baseline (64521.967 us; speedup 1.0000x reference)
//
#include <hip/hip_runtime.h>
#include <cstdint>
#include <cstddef>

// Problem constants
namespace {
constexpr int HD  = 1024;   // hidden
constexpr int LD  = 4;      // layers
constexpr int BD  = 64;     // batch
constexpr int TD  = 512;    // seq len
constexpr int IND = 128;    // input dim
constexpr int OD  = 128;    // out dim
constexpr int NBLK  = 200;  // persistent blocks in scan kernel
constexpr int NSLOT = 5;    // z ring depth
constexpr int KC    = 64;   // K chunk
constexpr int LBH = LD * BD * HD;
constexpr int BH  = BD * HD;
}

// ---------------------------------------------------------------------------
// Generic fp32 GEMM: C[M,N] = alpha * A[M,K] @ B[K,N] (+ addvec[N] broadcast)
// tile: 64 rows x 128 cols per block of 256 threads. M%64==0, N%128==0, K%64==0.
// ---------------------------------------------------------------------------
__global__ __launch_bounds__(256) void gemm_nn_k(
    const float* __restrict__ A, const float* __restrict__ Bm, float* __restrict__ C,
    int M, int N, int K, int ldb, float alpha, const float* __restrict__ addvec)
{
  __shared__ float a_lds[64][65];
  __shared__ __align__(16) float b_lds[KC][132];
  const int tid  = threadIdx.x;
  const int row0 = blockIdx.y * 64;
  const int col0 = blockIdx.x * 128;
  const int rg = tid >> 4, cg = tid & 15;
  (void)M;

  float acc[4][8];
  #pragma unroll
  for (int i = 0; i < 4; ++i)
    #pragma unroll
    for (int j = 0; j < 8; ++j) acc[i][j] = 0.f;

  for (int k0 = 0; k0 < K; k0 += KC) {
    #pragma unroll
    for (int i = 0; i < 4; ++i) {
      const int q = tid + i * 256;
      const int r = q >> 4;
      const int k4 = (q & 15) << 2;
      const float4 v = *(const float4*)(A + (size_t)(row0 + r) * K + k0 + k4);
      a_lds[r][k4 + 0] = v.x;
      a_lds[r][k4 + 1] = v.y;
      a_lds[r][k4 + 2] = v.z;
      a_lds[r][k4 + 3] = v.w;
    }
    #pragma unroll
    for (int i = 0; i < 8; ++i) {
      const int q = tid + i * 256;
      const int k = q >> 5;
      const int c4 = (q & 31) << 2;
      *(float4*)&b_lds[k][c4] = *(const float4*)(Bm + (size_t)(k0 + k) * ldb + col0 + c4);
    }
    __syncthreads();
    #pragma unroll 4
    for (int k = 0; k < KC; ++k) {
      float wv[8], av[4];
      *(float4*)&wv[0] = *(const float4*)&b_lds[k][cg * 8];
      *(float4*)&wv[4] = *(const float4*)&b_lds[k][cg * 8 + 4];
      #pragma unroll
      for (int i = 0; i < 4; ++i) av[i] = a_lds[rg * 4 + i][k];
      #pragma unroll
      for (int i = 0; i < 4; ++i)
        #pragma unroll
        for (int j = 0; j < 8; ++j)
          acc[i][j] = fmaf(av[i], wv[j], acc[i][j]);
    }
    __syncthreads();
  }

  #pragma unroll
  for (int i = 0; i < 4; ++i) {
    const int r = row0 + rg * 4 + i;
    #pragma unroll
    for (int j = 0; j < 8; ++j) {
      const int c = col0 + cg * 8 + j;
      float v = alpha * acc[i][j];
      if (addvec) v += addvec[c];
      C[(size_t)r * N + c] = v;
    }
  }
}

// ---------------------------------------------------------------------------
// Bias/const precompute:
//  cvec[m][h]  = bh_dense[m]+bh[m] + (sum_{j<m} 2^{m-1-j} d_j + 2^m bi) @ A_m
//  const_o[o]  = bo_dense+o_bias + (sum_j 2^{3-j} d_j + 16 bi) @ Wo
//  where d_j = by_dense[j]+by[j], A_m = Wh[m][0:H,:]
// ---------------------------------------------------------------------------
__global__ __launch_bounds__(256) void consts_k(
    const float* __restrict__ Wh, const float* __restrict__ bh_dense, const float* __restrict__ bh,
    const float* __restrict__ by_dense, const float* __restrict__ by, const float* __restrict__ bi,
    const float* __restrict__ Wo, const float* __restrict__ bo_dense, const float* __restrict__ o_bias,
    float* __restrict__ cvec, float* __restrict__ const_o)
{
  __shared__ float e_lds[HD];
  const int tid = threadIdx.x;
  if (blockIdx.x < 16) {
    const int m = blockIdx.x >> 2;
    const int hcol = ((blockIdx.x & 3) << 8) + tid;
    for (int k = tid; k < HD; k += 256) {
      float e = (float)(1 << m) * bi[k];
      for (int j = 0; j < m; ++j)
        e += (float)(1 << (m - 1 - j)) * (by_dense[j * HD + k] + by[j * HD + k]);
      e_lds[k] = e;
    }
    __syncthreads();
    float acc = bh_dense[m * HD + hcol] + bh[m * HD + hcol];
    for (int k = 0; k < HD; ++k)
      acc = fmaf(e_lds[k], Wh[(size_t)m * 2 * HD * HD + (size_t)k * HD + hcol], acc);
    cvec[m * HD + hcol] = acc;
  } else {
    if (tid < OD) {
      float acc = bo_dense[tid] + o_bias[tid];
      for (int k = 0; k < HD; ++k) {
        float e = 16.f * bi[k];
        e += 8.f * (by_dense[0 * HD + k] + by[0 * HD + k]);
        e += 4.f * (by_dense[1 * HD + k] + by[1 * HD + k]);
        e += 2.f * (by_dense[2 * HD + k] + by[2 * HD + k]);
        e += 1.f * (by_dense[3 * HD + k] + by[3 * HD + k]);
        acc = fmaf(e, Wo[(size_t)k * OD + tid], acc);
      }
      const_o[tid] = acc;
    }
  }
}

// ---------------------------------------------------------------------------
// Persistent wavefront scan kernel. One grid barrier per virtual step.
// At step v: compute z_m for t=v-m (all m independent):
//   z_m^t = sum_{j<m} 2^{m-1-j} relu(z_j^t + c_j) @ G_{j,m}
//         + 2^m x_t @ WiA_m + relu(z_m^{t-1} + c_m) @ B_m     (into z ring, atomic)
// and out[t'=v-1-j] += 2^{3-j} relu(z_j^{t'} + c_j) @ P_j.
// ---------------------------------------------------------------------------
__global__ __launch_bounds__(256, 1) void rnn_scan_k(
    const float* __restrict__ x,
    const float* __restrict__ Gmat,   // [6][H][H]
    const float* __restrict__ WiA,    // [4][IN][H]
    const float* __restrict__ Pmat,   // [4][H][OD]
    const float* __restrict__ Wh,     // raw input (B_m = Wh + m*2HH + HH)
    const float* __restrict__ cvec,   // [4][H]
    float* __restrict__ zring,        // [5][L][B][H]
    float* __restrict__ outp,         // [B][T][OD]
    int* __restrict__ bar)
{
  __shared__ float a_lds[64][65];
  __shared__ __align__(16) float b_lds[KC][132];
  const int tid = threadIdx.x;
  const int jid = blockIdx.x;
  const int rg = tid >> 4, cg = tid & 15;

  // ---- static job decode ----
  int jtype, jm = 0, jsrc = 0, jku = 0, jct = 0;
  if (jid < 160) {
    jtype = 0;
    int rem;
    if (jid < 16)      { jm = 0; rem = jid; }
    else if (jid < 48) { jm = 1; rem = jid - 16; }
    else if (jid < 96) { jm = 2; rem = jid - 48; }
    else               { jm = 3; rem = jid - 96; }
    jsrc = rem >> 4;
    jku  = (rem >> 3) & 1;
    jct  = rem & 7;
  } else if (jid < 192) {
    jtype = 1; jm = (jid - 160) >> 3; jct = (jid - 160) & 7;
  } else {
    jtype = 2; jsrc = (jid - 192) >> 1; jku = (jid - 192) & 1;
  }
  const int col0 = jct * 128;
  const int gb[4] = {0, 0, 1, 3};   // base index into G pair list per m

  int* cnt = bar;
  int* gen = bar + 32;

  for (int v = 0; v < TD + LD; ++v) {
    // ---- zero the slot that becomes the write target at step v+1 (dead now) ----
    {
      float* zp = zring + (size_t)((v + 1) % NSLOT) * LBH;
      for (int i = jid * 256 + tid; i < LBH; i += NBLK * 256)
        __hip_atomic_store(&zp[i], 0.f, __ATOMIC_RELAXED, __HIP_MEMORY_SCOPE_AGENT);
    }

    // ---- dynamic job setup ----
    const float* src = nullptr;
    const float* W   = nullptr;
    const float* cp  = nullptr;
    float* dst = nullptr;
    int src_rs = 0, ldb = 0, dst_rs = 0, kbase = 0, klen = 0;
    float scale = 1.f;
    bool active = false;

    if (jtype == 0) {
      const int t = v - jm;
      if (t >= 0 && t < TD) {
        if (jsrc < jm) {                       // G source: h_j^t
          const int j = jsrc;
          src = zring + (size_t)((t + j) % NSLOT) * LBH + (size_t)j * BH;
          cp = cvec + j * HD;
          scale = (float)(1 << (jm - 1 - j));
          W = Gmat + (size_t)(gb[jm] + j) * HD * HD;
          active = true;
        } else if (t >= 1) {                   // B source: h_m^{t-1}
          src = zring + (size_t)((v - 1) % NSLOT) * LBH + (size_t)jm * BH;
          cp = cvec + jm * HD;
          scale = 1.f;
          W = Wh + (size_t)jm * 2 * HD * HD + (size_t)HD * HD;
          active = true;
        }
        src_rs = HD; ldb = HD;
        kbase = jku * 512; klen = 512;
        dst = zring + (size_t)(v % NSLOT) * LBH + (size_t)jm * BH + col0;
        dst_rs = HD;
      }
    } else if (jtype == 1) {                   // x source (K=128)
      const int t = v - jm;
      if (t >= 0 && t < TD) {
        src = x + (size_t)t * IND; src_rs = TD * IND;
        scale = (float)(1 << jm);
        W = WiA + (size_t)jm * IND * HD; ldb = HD;
        kbase = 0; klen = IND;
        dst = zring + (size_t)(v % NSLOT) * LBH + (size_t)jm * BH + col0;
        dst_rs = HD;
        active = true;
      }
    } else {                                   // out projection of h_j^{v-1-j}
      const int j = jsrc;
      const int tp = v - 1 - j;
      if (tp >= 0 && tp < TD) {
        src = zring + (size_t)((v - 1) % NSLOT) * LBH + (size_t)j * BH;
        src_rs = HD;
        cp = cvec + j * HD;
        scale = (float)(1 << (3 - j));
        W = Pmat + (size_t)j * HD * OD; ldb = OD;
        kbase = jku * 512; klen = 512;
        dst = outp + (size_t)tp * OD; dst_rs = TD * OD;
        active = true;
      }
    }

    // ---- job GEMM: [64 x 128] tile, K = klen, atomic accumulate ----
    if (active) {
      float acc[4][8];
      #pragma unroll
      for (int i = 0; i < 4; ++i)
        #pragma unroll
        for (int j = 0; j < 8; ++j) acc[i][j] = 0.f;

      for (int k0 = 0; k0 < klen; k0 += KC) {
        #pragma unroll
        for (int i = 0; i < 4; ++i) {
          const int q = tid + i * 256;
          const int r = q >> 4;
          const int k4 = (q & 15) << 2;
          const int kg = kbase + k0 + k4;
          float4 zv = *(const float4*)(src + (size_t)r * src_rs + kg);
          if (cp) {
            const float4 cv = *(const float4*)(cp + kg);
            zv.x = fmaxf(zv.x + cv.x, 0.f);
            zv.y = fmaxf(zv.y + cv.y, 0.f);
            zv.z = fmaxf(zv.z + cv.z, 0.f);
            zv.w = fmaxf(zv.w + cv.w, 0.f);
          }
          a_lds[r][k4 + 0] = scale * zv.x;
          a_lds[r][k4 + 1] = scale * zv.y;
          a_lds[r][k4 + 2] = scale * zv.z;
          a_lds[r][k4 + 3] = scale * zv.w;
        }
        #pragma unroll
        for (int i = 0; i < 8; ++i) {
          const int q = tid + i * 256;
          const int k = q >> 5;
          const int c4 = (q & 31) << 2;
          *(float4*)&b_lds[k][c4] =
              *(const float4*)(W + (size_t)(kbase + k0 + k) * ldb + col0 + c4);
        }
        __syncthreads();
        #pragma unroll 4
        for (int k = 0; k < KC; ++k) {
          float wv[8], av[4];
          *(float4*)&wv[0] = *(const float4*)&b_lds[k][cg * 8];
          *(float4*)&wv[4] = *(const float4*)&b_lds[k][cg * 8 + 4];
          #pragma unroll
          for (int i = 0; i < 4; ++i) av[i] = a_lds[rg * 4 + i][k];
          #pragma unroll
          for (int i = 0; i < 4; ++i)
            #pragma unroll
            for (int j = 0; j < 8; ++j)
              acc[i][j] = fmaf(av[i], wv[j], acc[i][j]);
        }
        __syncthreads();
      }
      #pragma unroll
      for (int i = 0; i < 4; ++i) {
        const int r = rg * 4 + i;
        #pragma unroll
        for (int j = 0; j < 8; ++j)
          atomicAdd(dst + (size_t)r * dst_rs + cg * 8 + j, acc[i][j]);
      }
    }

    // ---- grid barrier (monotonic counter + generation) ----
    __syncthreads();
    if (tid == 0) {
      const int prev = __hip_atomic_fetch_add(cnt, 1, __ATOMIC_ACQ_REL, __HIP_MEMORY_SCOPE_AGENT);
      if (prev == (v + 1) * NBLK - 1) {
        __hip_atomic_store(gen, v + 1, __ATOMIC_RELEASE, __HIP_MEMORY_SCOPE_AGENT);
      } else {
        while (__hip_atomic_load(gen, __ATOMIC_RELAXED, __HIP_MEMORY_SCOPE_AGENT) < v + 1)
          __builtin_amdgcn_s_sleep(16);
        __builtin_amdgcn_fence(__ATOMIC_ACQUIRE, "agent");
      }
    }
    __syncthreads();
  }
}

// ---------------------------------------------------------------------------
extern "C" void kernel_launch(void* const* d_in, const int* in_sizes, int n_in,
                              void* d_out, int out_size, void* d_ws, size_t ws_size,
                              hipStream_t stream)
{
  (void)in_sizes; (void)n_in; (void)out_size; (void)ws_size;

  const float* x        = (const float*)d_in[0];
  const float* Wi       = (const float*)d_in[1];
  const float* bi       = (const float*)d_in[2];
  const float* Wh       = (const float*)d_in[3];
  const float* bh_dense = (const float*)d_in[4];
  const float* bh       = (const float*)d_in[5];
  const float* Wy       = (const float*)d_in[6];
  const float* by_dense = (const float*)d_in[7];
  const float* by       = (const float*)d_in[8];
  const float* Wo       = (const float*)d_in[9];
  const float* bo_dense = (const float*)d_in[10];
  const float* o_bias   = (const float*)d_in[11];
  float* out = (float*)d_out;
  float* ws  = (float*)d_ws;

  size_t off = 0;
  float* G       = ws + off; off += (size_t)6 * HD * HD;     // 6 composed Wy[j]@A_m
  float* WiA     = ws + off; off += (size_t)4 * IND * HD;    // Wi@A_m
  float* P       = ws + off; off += (size_t)4 * HD * OD;     // Wy[j]@Wo
  float* WiWo    = ws + off; off += (size_t)IND * OD;
  float* cvec    = ws + off; off += (size_t)4 * HD;
  float* const_o = ws + off; off += OD;
  off = (off + 63) & ~(size_t)63;
  float* zring   = ws + off; off += (size_t)NSLOT * LBH;
  int*   bar     = (int*)(ws + off);

  // zero z ring + barrier state (ws is poisoned before every call)
  hipMemsetAsync(zring, 0, (size_t)NSLOT * LBH * sizeof(float) + 256, stream);

  // bias constants
  consts_k<<<17, 256, 0, stream>>>(Wh, bh_dense, bh, by_dense, by, bi,
                                   Wo, bo_dense, o_bias, cvec, const_o);

  // composed matrices
  static const int pj[6] = {0, 0, 1, 0, 1, 2};
  static const int pm[6] = {1, 2, 2, 3, 3, 3};
  for (int p = 0; p < 6; ++p)
    gemm_nn_k<<<dim3(8, 16), 256, 0, stream>>>(
        Wy + (size_t)pj[p] * HD * HD, Wh + (size_t)pm[p] * 2 * HD * HD,
        G + (size_t)p * HD * HD, HD, HD, HD, HD, 1.f, nullptr);
  for (int m = 0; m < 4; ++m)
    gemm_nn_k<<<dim3(8, 2), 256, 0, stream>>>(
        Wi, Wh + (size_t)m * 2 * HD * HD, WiA + (size_t)m * IND * HD,
        IND, HD, HD, HD, 1.f, nullptr);
  for (int j = 0; j < 4; ++j)
    gemm_nn_k<<<dim3(1, 16), 256, 0, stream>>>(
        Wy + (size_t)j * HD * HD, Wo, P + (size_t)j * HD * OD,
        HD, OD, HD, OD, 1.f, nullptr);
  gemm_nn_k<<<dim3(1, 2), 256, 0, stream>>>(Wi, Wo, WiWo, IND, OD, HD, OD, 1.f, nullptr);

  // out = 16 * x @ (Wi@Wo) + const_o  (exact fp32 dominant term)
  gemm_nn_k<<<dim3(1, (BD * TD) / 64), 256, 0, stream>>>(
      x, WiWo, out, BD * TD, OD, IND, OD, 16.f, const_o);

  // persistent wavefront scan
  rnn_scan_k<<<NBLK, 256, 0, stream>>>(x, G, WiA, P, Wh, cvec, zring, out, bar);
}

// Round 3
// 29294.937 us; speedup vs baseline: 2.2025x; 2.2025x over previous
//
#include <hip/hip_runtime.h>
#include <cstdint>
#include <cstddef>

namespace {
constexpr int HD  = 1024;
constexpr int LD  = 4;
constexpr int BD  = 64;
constexpr int TD  = 512;
constexpr int IND = 128;
constexpr int OD  = 128;
constexpr int NSLOT = 5;
constexpr int LBH = LD * BD * HD;   // 262144
constexpr int BH  = BD * HD;        // 65536
constexpr int UNITS = 1408;         // canonical work units per step
constexpr size_t HH = (size_t)HD * HD;
}

// ---------------------------------------------------------------------------
// Generic fp32 GEMM tile (64 rows x 128 cols, 256 threads), for prep kernels.
// C[row0.., col0..] = alpha * A @ B (+ addvec). K multiple of 64.
// ---------------------------------------------------------------------------
__device__ __forceinline__ void gemm_tile(
    const float* __restrict__ A, int lda, const float* __restrict__ Bm, int ldb,
    float* __restrict__ C, int ldc, int K, int row0, int col0,
    float alpha, const float* __restrict__ addvec)
{
  __shared__ float a_lds[64][65];
  __shared__ __align__(16) float b_lds[64][132];
  const int tid = threadIdx.x;
  const int rg = tid >> 4, cg = tid & 15;

  float acc[4][8];
  #pragma unroll
  for (int i = 0; i < 4; ++i)
    #pragma unroll
    for (int j = 0; j < 8; ++j) acc[i][j] = 0.f;

  for (int k0 = 0; k0 < K; k0 += 64) {
    #pragma unroll
    for (int i = 0; i < 4; ++i) {
      const int q = tid + i * 256;
      const int r = q >> 4;
      const int k4 = (q & 15) << 2;
      const float4 v = *(const float4*)(A + (size_t)(row0 + r) * lda + k0 + k4);
      a_lds[r][k4 + 0] = v.x; a_lds[r][k4 + 1] = v.y;
      a_lds[r][k4 + 2] = v.z; a_lds[r][k4 + 3] = v.w;
    }
    #pragma unroll
    for (int i = 0; i < 8; ++i) {
      const int q = tid + i * 256;
      const int k = q >> 5;
      const int c4 = (q & 31) << 2;
      *(float4*)&b_lds[k][c4] = *(const float4*)(Bm + (size_t)(k0 + k) * ldb + col0 + c4);
    }
    __syncthreads();
    #pragma unroll 4
    for (int k = 0; k < 64; ++k) {
      float wv[8], av[4];
      *(float4*)&wv[0] = *(const float4*)&b_lds[k][cg * 8];
      *(float4*)&wv[4] = *(const float4*)&b_lds[k][cg * 8 + 4];
      #pragma unroll
      for (int i = 0; i < 4; ++i) av[i] = a_lds[rg * 4 + i][k];
      #pragma unroll
      for (int i = 0; i < 4; ++i)
        #pragma unroll
        for (int j = 0; j < 8; ++j)
          acc[i][j] = fmaf(av[i], wv[j], acc[i][j]);
    }
    __syncthreads();
  }

  #pragma unroll
  for (int i = 0; i < 4; ++i) {
    const int r = row0 + rg * 4 + i;
    #pragma unroll
    for (int j = 0; j < 8; ++j) {
      const int c = col0 + cg * 8 + j;
      float v = alpha * acc[i][j];
      if (addvec) v += addvec[c];
      C[(size_t)r * ldc + c] = v;
    }
  }
}

// ---------------------------------------------------------------------------
// prep1: all weight compositions in one launch (898 blocks).
// ---------------------------------------------------------------------------
__global__ __launch_bounds__(256) void prep1_k(
    const float* __restrict__ Wy, const float* __restrict__ Wh,
    const float* __restrict__ Wi, const float* __restrict__ Wo,
    float* __restrict__ G, float* __restrict__ WiA,
    float* __restrict__ P, float* __restrict__ WiWo)
{
  static const int pj[6] = {0, 0, 1, 0, 1, 2};
  static const int pm[6] = {1, 2, 2, 3, 3, 3};
  const int bid = blockIdx.x;
  const float *A, *Bm; float* C; int lda, ldb, ldc, row0, col0;
  if (bid < 768) {
    const int p = bid >> 7, rr = bid & 127;
    A = Wy + (size_t)pj[p] * HH; lda = HD;
    Bm = Wh + (size_t)pm[p] * 2 * HH; ldb = HD;
    C = G + (size_t)p * HH; ldc = HD;
    row0 = (rr >> 3) * 64; col0 = (rr & 7) * 128;
  } else if (bid < 832) {
    const int r = bid - 768, m = r >> 4;
    A = Wi; lda = HD;
    Bm = Wh + (size_t)m * 2 * HH; ldb = HD;
    C = WiA + (size_t)m * IND * HD; ldc = HD;
    row0 = ((r >> 3) & 1) * 64; col0 = (r & 7) * 128;
  } else if (bid < 896) {
    const int r = bid - 832, j = r >> 4;
    A = Wy + (size_t)j * HH; lda = HD;
    Bm = Wo; ldb = OD;
    C = P + (size_t)j * HD * OD; ldc = OD;
    row0 = (r & 15) * 64; col0 = 0;
  } else {
    const int r = bid - 896;
    A = Wi; lda = HD; Bm = Wo; ldb = OD; C = WiWo; ldc = OD;
    row0 = r * 64; col0 = 0;
  }
  gemm_tile(A, lda, Bm, ldb, C, ldc, HD, row0, col0, 1.f, nullptr);
}

// prep2: out = 16 * x @ WiWo + const_o   (512 blocks)
__global__ __launch_bounds__(256) void prep2_k(
    const float* __restrict__ x, const float* __restrict__ WiWo,
    const float* __restrict__ const_o, float* __restrict__ out)
{
  gemm_tile(x, IND, WiWo, OD, out, OD, IND, blockIdx.x * 64, 0, 16.f, const_o);
}

// ---------------------------------------------------------------------------
// Bias/const precompute.
// ---------------------------------------------------------------------------
__global__ __launch_bounds__(256) void consts_k(
    const float* __restrict__ Wh, const float* __restrict__ bh_dense, const float* __restrict__ bh,
    const float* __restrict__ by_dense, const float* __restrict__ by, const float* __restrict__ bi,
    const float* __restrict__ Wo, const float* __restrict__ bo_dense, const float* __restrict__ o_bias,
    float* __restrict__ cvec, float* __restrict__ const_o)
{
  __shared__ float e_lds[HD];
  const int tid = threadIdx.x;
  if (blockIdx.x < 16) {
    const int m = blockIdx.x >> 2;
    const int hcol = ((blockIdx.x & 3) << 8) + tid;
    for (int k = tid; k < HD; k += 256) {
      float e = (float)(1 << m) * bi[k];
      for (int j = 0; j < m; ++j)
        e += (float)(1 << (m - 1 - j)) * (by_dense[j * HD + k] + by[j * HD + k]);
      e_lds[k] = e;
    }
    __syncthreads();
    float acc = bh_dense[m * HD + hcol] + bh[m * HD + hcol];
    for (int k = 0; k < HD; ++k)
      acc = fmaf(e_lds[k], Wh[(size_t)m * 2 * HH + (size_t)k * HD + hcol], acc);
    cvec[m * HD + hcol] = acc;
  } else {
    if (tid < OD) {
      float acc = bo_dense[tid] + o_bias[tid];
      for (int k = 0; k < HD; ++k) {
        float e = 16.f * bi[k];
        e += 8.f * (by_dense[0 * HD + k] + by[0 * HD + k]);
        e += 4.f * (by_dense[1 * HD + k] + by[1 * HD + k]);
        e += 2.f * (by_dense[2 * HD + k] + by[2 * HD + k]);
        e += 1.f * (by_dense[3 * HD + k] + by[3 * HD + k]);
        acc = fmaf(e, Wo[(size_t)k * OD + tid], acc);
      }
      const_o[tid] = acc;
    }
  }
}

// ---------------------------------------------------------------------------
// Persistent wavefront scan. 516 grid barriers. nblk blocks (2/CU), each
// owns ~2.75 canonical units/step: unit = [64 rows x 64 cols] x 128-K chunk.
//   u < 1280 : h-path, m prefix {0,128,384,768}; rel: src=rel>>7, ct=(rel>>3)&15, kc=rel&7
//   u < 1344 : x-path, m=(u-1280)>>4, ct=(u-1280)&15 (K=128)
//   u < 1408 : out-path, r=u-1344: j=r>>4, ct=(r>>3)&1, kc=r&7
// ---------------------------------------------------------------------------
__global__ __launch_bounds__(256) void rnn_scan_k(
    const float* __restrict__ x,
    const float* __restrict__ Gmat,   // [6][H][H]
    const float* __restrict__ WiA,    // [4][IN][H]
    const float* __restrict__ Pmat,   // [4][H][OD]
    const float* __restrict__ Wh,     // raw input (B_m = Wh + m*2HH + HH)
    const float* __restrict__ cvec,   // [4][H]
    float* __restrict__ zring,        // [5][L][B][H]
    float* __restrict__ outp,         // [B][T][OD]
    int* __restrict__ bar, int nblk)
{
  // A tile is 64 rows x 128 K-cols. Stride 129 (odd): scalar reads
  // a_lds[rg*4+i][k] -> banks 4*rg+(i+k): 2-way = free; scalar staging
  // stores land on consecutive banks (129 % 32 == 1): conflict-free.
  __shared__ float a_lds[64][129];
  __shared__ __align__(16) float b_lds[128][68];  // b128 reads 2-way (free)
  const int tid = threadIdx.x, bid = blockIdx.x;
  const int rg = tid >> 4, cg = tid & 15;         // output 4x4 sub-tile coords
  const int ar = tid & 63, akq = tid >> 6;        // A staging: row, k-quarter
  const int u0 = (UNITS * bid) / nblk;
  const int u1 = (UNITS * (bid + 1)) / nblk;
  const int gb[4] = {0, 0, 1, 3};
  int* cnt = bar;
  int* gen = bar + 32;

  for (int v = 0; v < TD + LD; ++v) {
    // zero the slot that becomes the write target at step v+1 (dead at step v)
    {
      float* zp = zring + (size_t)((v + 1) % NSLOT) * LBH;
      for (int i = bid * 256 + tid; i < LBH; i += nblk * 256)
        __hip_atomic_store(&zp[i], 0.f, __ATOMIC_RELAXED, __HIP_MEMORY_SCOPE_AGENT);
    }

    float acc[4][4];
    #pragma unroll
    for (int i = 0; i < 4; ++i)
      #pragma unroll
      for (int j = 0; j < 4; ++j) acc[i][j] = 0.f;
    float* cur = nullptr;
    int cldd = 0;

    for (int u = u0; u < u1; ++u) {
      // ---- decode unit (uniform across block) ----
      const float* A = nullptr; const float* W = nullptr; const float* cv = nullptr;
      float* dst = nullptr;
      int lda = 0, ldw = 0, ldd = 0;
      float scale = 1.f;

      if (u < 1280) {
        int m, rel;
        if (u < 128)      { m = 0; rel = u; }
        else if (u < 384) { m = 1; rel = u - 128; }
        else if (u < 768) { m = 2; rel = u - 384; }
        else              { m = 3; rel = u - 768; }
        const int src = rel >> 7, ct = (rel >> 3) & 15, kc = rel & 7;
        const int t = v - m;
        if (t >= 0 && t < TD) {
          if (src < m) {                       // G source: h_src^t
            const int j = src;
            A  = zring + (size_t)((t + j) % NSLOT) * LBH + (size_t)j * BH + kc * 128;
            cv = cvec + j * HD + kc * 128;
            scale = (float)(1 << (m - 1 - j));
            W = Gmat + (size_t)(gb[m] + j) * HH + (size_t)(kc * 128) * HD + ct * 64;
            lda = HD; ldw = HD;
          } else if (t >= 1) {                 // B source: h_m^{t-1}
            A  = zring + (size_t)((v - 1) % NSLOT) * LBH + (size_t)m * BH + kc * 128;
            cv = cvec + m * HD + kc * 128;
            scale = 1.f;
            W = Wh + (size_t)m * 2 * HH + HH + (size_t)(kc * 128) * HD + ct * 64;
            lda = HD; ldw = HD;
          }
          dst = zring + (size_t)(v % NSLOT) * LBH + (size_t)m * BH + ct * 64;
          ldd = HD;
        }
      } else if (u < 1344) {
        const int r = u - 1280, m = r >> 4, ct = r & 15;
        const int t = v - m;
        if (t >= 0 && t < TD) {
          A = x + (size_t)t * IND; lda = TD * IND;
          scale = (float)(1 << m);
          W = WiA + (size_t)m * IND * HD + ct * 64; ldw = HD;
          dst = zring + (size_t)(v % NSLOT) * LBH + (size_t)m * BH + ct * 64;
          ldd = HD;
        }
      } else {
        const int r = u - 1344, j = r >> 4, ct = (r >> 3) & 1, kc = r & 7;
        const int tp = v - 1 - j;
        if (tp >= 0 && tp < TD) {
          A  = zring + (size_t)((v - 1) % NSLOT) * LBH + (size_t)j * BH + kc * 128;
          lda = HD;
          cv = cvec + j * HD + kc * 128;
          scale = (float)(1 << (3 - j));
          W = Pmat + (size_t)j * HD * OD + (size_t)(kc * 128) * OD + ct * 64; ldw = OD;
          dst = outp + (size_t)tp * OD + ct * 64; ldd = TD * OD;
        }
      }
      if (!A || !W) continue;   // inactive unit (uniform)

      if (dst != cur) {
        if (cur) {
          #pragma unroll
          for (int i = 0; i < 4; ++i)
            #pragma unroll
            for (int j = 0; j < 4; ++j) {
              atomicAdd(cur + (size_t)(rg * 4 + i) * cldd + cg * 4 + j, acc[i][j]);
              acc[i][j] = 0.f;
            }
        }
        cur = dst; cldd = ldd;
      }

      // ---- stage A [64 x 128] (relu+bias+scale on load), scalar stores ----
      {
        const float4* cvp = (const float4*)cv;
        #pragma unroll
        for (int j = 0; j < 8; ++j) {
          const int col = akq * 32 + j * 4;
          float4 v4 = *(const float4*)(A + (size_t)ar * lda + col);
          if (cv) {
            const float4 c4 = cvp[col >> 2];
            v4.x = fmaxf(v4.x + c4.x, 0.f);
            v4.y = fmaxf(v4.y + c4.y, 0.f);
            v4.z = fmaxf(v4.z + c4.z, 0.f);
            v4.w = fmaxf(v4.w + c4.w, 0.f);
          }
          a_lds[ar][col + 0] = scale * v4.x;
          a_lds[ar][col + 1] = scale * v4.y;
          a_lds[ar][col + 2] = scale * v4.z;
          a_lds[ar][col + 3] = scale * v4.w;
        }
      }
      // ---- stage B [128 x 64] ----
      #pragma unroll
      for (int p = 0; p < 8; ++p) {
        const int q = tid + p * 256;
        const int k = q >> 4, c4 = (q & 15) << 2;
        *(float4*)&b_lds[k][c4] = *(const float4*)(W + (size_t)k * ldw + c4);
      }
      __syncthreads();

      // ---- inner: 128-K, k-unroll 2; A scalar broadcast, B via b128 ----
      #pragma unroll 8
      for (int k2 = 0; k2 < 64; ++k2) {
        const int k = k2 * 2;
        const float4 b0 = *(const float4*)&b_lds[k][cg * 4];
        const float4 b1 = *(const float4*)&b_lds[k + 1][cg * 4];
        #pragma unroll
        for (int i = 0; i < 4; ++i) {
          const float a0 = a_lds[rg * 4 + i][k];
          const float a1 = a_lds[rg * 4 + i][k + 1];
          acc[i][0] = fmaf(a0, b0.x, acc[i][0]);
          acc[i][1] = fmaf(a0, b0.y, acc[i][1]);
          acc[i][2] = fmaf(a0, b0.z, acc[i][2]);
          acc[i][3] = fmaf(a0, b0.w, acc[i][3]);
          acc[i][0] = fmaf(a1, b1.x, acc[i][0]);
          acc[i][1] = fmaf(a1, b1.y, acc[i][1]);
          acc[i][2] = fmaf(a1, b1.z, acc[i][2]);
          acc[i][3] = fmaf(a1, b1.w, acc[i][3]);
        }
      }
      __syncthreads();
    }

    if (cur) {
      #pragma unroll
      for (int i = 0; i < 4; ++i)
        #pragma unroll
        for (int j = 0; j < 4; ++j)
          atomicAdd(cur + (size_t)(rg * 4 + i) * cldd + cg * 4 + j, acc[i][j]);
    }

    // ---- grid barrier ----
    __syncthreads();
    if (tid == 0) {
      const int prev = __hip_atomic_fetch_add(cnt, 1, __ATOMIC_ACQ_REL, __HIP_MEMORY_SCOPE_AGENT);
      if (prev == (v + 1) * nblk - 1) {
        __hip_atomic_store(gen, v + 1, __ATOMIC_RELEASE, __HIP_MEMORY_SCOPE_AGENT);
      } else {
        while (__hip_atomic_load(gen, __ATOMIC_RELAXED, __HIP_MEMORY_SCOPE_AGENT) < v + 1)
          __builtin_amdgcn_s_sleep(4);
        __builtin_amdgcn_fence(__ATOMIC_ACQUIRE, "agent");
      }
    }
    __syncthreads();
  }
}

// ---------------------------------------------------------------------------
extern "C" void kernel_launch(void* const* d_in, const int* in_sizes, int n_in,
                              void* d_out, int out_size, void* d_ws, size_t ws_size,
                              hipStream_t stream)
{
  (void)in_sizes; (void)n_in; (void)out_size; (void)ws_size;

  const float* x        = (const float*)d_in[0];
  const float* Wi       = (const float*)d_in[1];
  const float* bi       = (const float*)d_in[2];
  const float* Wh       = (const float*)d_in[3];
  const float* bh_dense = (const float*)d_in[4];
  const float* bh       = (const float*)d_in[5];
  const float* Wy       = (const float*)d_in[6];
  const float* by_dense = (const float*)d_in[7];
  const float* by       = (const float*)d_in[8];
  const float* Wo       = (const float*)d_in[9];
  const float* bo_dense = (const float*)d_in[10];
  const float* o_bias   = (const float*)d_in[11];
  float* out = (float*)d_out;
  float* ws  = (float*)d_ws;

  size_t off = 0;
  float* G       = ws + off; off += (size_t)6 * HH;
  float* WiA     = ws + off; off += (size_t)4 * IND * HD;
  float* P       = ws + off; off += (size_t)4 * HD * OD;
  float* WiWo    = ws + off; off += (size_t)IND * OD;
  float* cvec    = ws + off; off += (size_t)4 * HD;
  float* const_o = ws + off; off += OD;
  off = (off + 63) & ~(size_t)63;
  float* zring   = ws + off; off += (size_t)NSLOT * LBH;
  int*   bar     = (int*)(ws + off);

  // co-residency guard: 66.2KB LDS/block -> 2 blocks/CU (132.5 <= 160KB).
  int occ = 2;
  if (hipOccupancyMaxActiveBlocksPerMultiprocessor(&occ, rnn_scan_k, 256, 0) != hipSuccess)
    occ = 2;
  if (occ < 1) occ = 1;
  if (occ > 2) occ = 2;
  const int nblk = 256 * occ;

  hipMemsetAsync(zring, 0, (size_t)NSLOT * LBH * sizeof(float) + 256, stream);

  consts_k<<<17, 256, 0, stream>>>(Wh, bh_dense, bh, by_dense, by, bi,
                                   Wo, bo_dense, o_bias, cvec, const_o);
  prep1_k<<<898, 256, 0, stream>>>(Wy, Wh, Wi, Wo, G, WiA, P, WiWo);
  prep2_k<<<512, 256, 0, stream>>>(x, WiWo, const_o, out);
  rnn_scan_k<<<nblk, 256, 0, stream>>>(x, G, WiA, P, Wh, cvec, zring, out, bar, nblk);
}

// Round 4
// 20159.743 us; speedup vs baseline: 3.2005x; 1.4531x over previous
//
#include <hip/hip_runtime.h>
#include <cstdint>
#include <cstddef>

namespace {
constexpr int HD  = 1024;
constexpr int LD  = 4;
constexpr int BD  = 64;
constexpr int TD  = 512;
constexpr int IND = 128;
constexpr int OD  = 128;
constexpr int NSLOT = 5;
constexpr int LBH = LD * BD * HD;   // 262144
constexpr int BH  = BD * HD;        // 65536
constexpr int UNITS = 2816;         // units per step (h/x: 2688, out: 128)
constexpr size_t HH = (size_t)HD * HD;
}

typedef unsigned short ushort_t;
typedef __attribute__((ext_vector_type(8))) short short8x;
typedef __attribute__((ext_vector_type(4))) float f32x4;

__device__ __forceinline__ ushort_t f2bf(float f) {
  unsigned u = __builtin_bit_cast(unsigned, f);
  u += 0x7FFFu + ((u >> 16) & 1u);          // RNE
  return (ushort_t)(u >> 16);
}
__device__ __forceinline__ float bf2f(ushort_t h) {
  return __builtin_bit_cast(float, (unsigned)h << 16);
}
__device__ __forceinline__ void split3(float f, ushort_t& h1, ushort_t& h2, ushort_t& h3) {
  h1 = f2bf(f); float r = f - bf2f(h1);
  h2 = f2bf(r); r -= bf2f(h2);
  h3 = f2bf(r);
}

// ---------------------------------------------------------------------------
// fp32 GEMM tile (64x128, 256 thr) for prep kernels (unchanged, proven).
// ---------------------------------------------------------------------------
__device__ __forceinline__ void gemm_tile(
    const float* __restrict__ A, int lda, const float* __restrict__ Bm, int ldb,
    float* __restrict__ C, int ldc, int K, int row0, int col0,
    float alpha, const float* __restrict__ addvec)
{
  __shared__ float a_lds[64][65];
  __shared__ __align__(16) float b_lds[64][132];
  const int tid = threadIdx.x;
  const int rg = tid >> 4, cg = tid & 15;

  float acc[4][8];
  #pragma unroll
  for (int i = 0; i < 4; ++i)
    #pragma unroll
    for (int j = 0; j < 8; ++j) acc[i][j] = 0.f;

  for (int k0 = 0; k0 < K; k0 += 64) {
    #pragma unroll
    for (int i = 0; i < 4; ++i) {
      const int q = tid + i * 256;
      const int r = q >> 4;
      const int k4 = (q & 15) << 2;
      const float4 v = *(const float4*)(A + (size_t)(row0 + r) * lda + k0 + k4);
      a_lds[r][k4 + 0] = v.x; a_lds[r][k4 + 1] = v.y;
      a_lds[r][k4 + 2] = v.z; a_lds[r][k4 + 3] = v.w;
    }
    #pragma unroll
    for (int i = 0; i < 8; ++i) {
      const int q = tid + i * 256;
      const int k = q >> 5;
      const int c4 = (q & 31) << 2;
      *(float4*)&b_lds[k][c4] = *(const float4*)(Bm + (size_t)(k0 + k) * ldb + col0 + c4);
    }
    __syncthreads();
    #pragma unroll 4
    for (int k = 0; k < 64; ++k) {
      float wv[8], av[4];
      *(float4*)&wv[0] = *(const float4*)&b_lds[k][cg * 8];
      *(float4*)&wv[4] = *(const float4*)&b_lds[k][cg * 8 + 4];
      #pragma unroll
      for (int i = 0; i < 4; ++i) av[i] = a_lds[rg * 4 + i][k];
      #pragma unroll
      for (int i = 0; i < 4; ++i)
        #pragma unroll
        for (int j = 0; j < 8; ++j)
          acc[i][j] = fmaf(av[i], wv[j], acc[i][j]);
    }
    __syncthreads();
  }

  #pragma unroll
  for (int i = 0; i < 4; ++i) {
    const int r = row0 + rg * 4 + i;
    #pragma unroll
    for (int j = 0; j < 8; ++j) {
      const int c = col0 + cg * 8 + j;
      float v = alpha * acc[i][j];
      if (addvec) v += addvec[c];
      C[(size_t)r * ldc + c] = v;
    }
  }
}

__global__ __launch_bounds__(256) void prep1_k(
    const float* __restrict__ Wy, const float* __restrict__ Wh,
    const float* __restrict__ Wi, const float* __restrict__ Wo,
    float* __restrict__ G, float* __restrict__ WiA,
    float* __restrict__ P, float* __restrict__ WiWo)
{
  static const int pj[6] = {0, 0, 1, 0, 1, 2};
  static const int pm[6] = {1, 2, 2, 3, 3, 3};
  const int bid = blockIdx.x;
  const float *A, *Bm; float* C; int lda, ldb, ldc, row0, col0;
  if (bid < 768) {
    const int p = bid >> 7, rr = bid & 127;
    A = Wy + (size_t)pj[p] * HH; lda = HD;
    Bm = Wh + (size_t)pm[p] * 2 * HH; ldb = HD;
    C = G + (size_t)p * HH; ldc = HD;
    row0 = (rr >> 3) * 64; col0 = (rr & 7) * 128;
  } else if (bid < 832) {
    const int r = bid - 768, m = r >> 4;
    A = Wi; lda = HD;
    Bm = Wh + (size_t)m * 2 * HH; ldb = HD;
    C = WiA + (size_t)m * IND * HD; ldc = HD;
    row0 = ((r >> 3) & 1) * 64; col0 = (r & 7) * 128;
  } else if (bid < 896) {
    const int r = bid - 832, j = r >> 4;
    A = Wy + (size_t)j * HH; lda = HD;
    Bm = Wo; ldb = OD;
    C = P + (size_t)j * HD * OD; ldc = OD;
    row0 = (r & 15) * 64; col0 = 0;
  } else {
    const int r = bid - 896;
    A = Wi; lda = HD; Bm = Wo; ldb = OD; C = WiWo; ldc = OD;
    row0 = r * 64; col0 = 0;
  }
  gemm_tile(A, lda, Bm, ldb, C, ldc, HD, row0, col0, 1.f, nullptr);
}

__global__ __launch_bounds__(256) void prep2_k(
    const float* __restrict__ x, const float* __restrict__ WiWo,
    const float* __restrict__ const_o, float* __restrict__ out)
{
  gemm_tile(x, IND, WiWo, OD, out, OD, IND, blockIdx.x * 64, 0, 16.f, const_o);
}

__global__ __launch_bounds__(256) void consts_k(
    const float* __restrict__ Wh, const float* __restrict__ bh_dense, const float* __restrict__ bh,
    const float* __restrict__ by_dense, const float* __restrict__ by, const float* __restrict__ bi,
    const float* __restrict__ Wo, const float* __restrict__ bo_dense, const float* __restrict__ o_bias,
    float* __restrict__ cvec, float* __restrict__ const_o)
{
  __shared__ float e_lds[HD];
  const int tid = threadIdx.x;
  if (blockIdx.x < 16) {
    const int m = blockIdx.x >> 2;
    const int hcol = ((blockIdx.x & 3) << 8) + tid;
    for (int k = tid; k < HD; k += 256) {
      float e = (float)(1 << m) * bi[k];
      for (int j = 0; j < m; ++j)
        e += (float)(1 << (m - 1 - j)) * (by_dense[j * HD + k] + by[j * HD + k]);
      e_lds[k] = e;
    }
    __syncthreads();
    float acc = bh_dense[m * HD + hcol] + bh[m * HD + hcol];
    for (int k = 0; k < HD; ++k)
      acc = fmaf(e_lds[k], Wh[(size_t)m * 2 * HH + (size_t)k * HD + hcol], acc);
    cvec[m * HD + hcol] = acc;
  } else {
    if (tid < OD) {
      float acc = bo_dense[tid] + o_bias[tid];
      for (int k = 0; k < HD; ++k) {
        float e = 16.f * bi[k];
        e += 8.f * (by_dense[0 * HD + k] + by[0 * HD + k]);
        e += 4.f * (by_dense[1 * HD + k] + by[1 * HD + k]);
        e += 2.f * (by_dense[2 * HD + k] + by[2 * HD + k]);
        e += 1.f * (by_dense[3 * HD + k] + by[3 * HD + k]);
        acc = fmaf(e, Wo[(size_t)k * OD + tid], acc);
      }
      const_o[tid] = acc;
    }
  }
}

// ---------------------------------------------------------------------------
// prep3: split every scan weight matrix W[k][n] into 3 bf16 planes, stored
// TRANSPOSED wT[plane][n][k] (k contiguous -> direct MFMA B-frag reads).
//   mats 0..9  (1024x1024): G0..G5, B0..B3 (=Wh[m] bottom half)  -> wTh
//   mats 10..13 (128x1024):  WiA_m                                -> wTx
//   mats 14..17 (1024x128):  P_j                                  -> wTp
// 2816 blocks, one 64x64 tile each.
// ---------------------------------------------------------------------------
__global__ __launch_bounds__(256) void prep3_k(
    const float* __restrict__ G, const float* __restrict__ Wh,
    const float* __restrict__ WiA, const float* __restrict__ P,
    ushort_t* __restrict__ wTh, ushort_t* __restrict__ wTx, ushort_t* __restrict__ wTp)
{
  __shared__ ushort_t tl[3][64][66];
  const int tid = threadIdx.x, bid = blockIdx.x;
  const float* src; ushort_t* dstb; int ld, dstK, k0, n0; size_t PS;
  if (bid < 2560) {
    const int mat = bid >> 8, rr = bid & 255;
    k0 = (rr >> 4) * 64; n0 = (rr & 15) * 64;
    src = (mat < 6) ? (G + (size_t)mat * HH) : (Wh + (size_t)(mat - 6) * 2 * HH + HH);
    ld = 1024; dstb = wTh + (size_t)mat * 3 * HH; PS = HH; dstK = 1024;
  } else if (bid < 2688) {
    const int r = bid - 2560, mat = r >> 5, rr = r & 31;
    k0 = (rr >> 4) * 64; n0 = (rr & 15) * 64;
    src = WiA + (size_t)mat * IND * HD; ld = 1024;
    dstb = wTx + (size_t)mat * 3 * 131072; PS = 131072; dstK = 128;
  } else {
    const int r = bid - 2688, mat = r >> 5, rr = r & 31;
    k0 = (rr >> 1) * 64; n0 = (rr & 1) * 64;
    src = P + (size_t)mat * HD * OD; ld = 128;
    dstb = wTp + (size_t)mat * 3 * 131072; PS = 131072; dstK = 1024;
  }
  #pragma unroll
  for (int i = 0; i < 4; ++i) {
    const int q = tid + i * 256, kr = q >> 4, n4 = (q & 15) * 4;
    const float4 vv = *(const float4*)(src + (size_t)(k0 + kr) * ld + n0 + n4);
    ushort_t h1, h2, h3;
    split3(vv.x, h1, h2, h3); tl[0][n4+0][kr]=h1; tl[1][n4+0][kr]=h2; tl[2][n4+0][kr]=h3;
    split3(vv.y, h1, h2, h3); tl[0][n4+1][kr]=h1; tl[1][n4+1][kr]=h2; tl[2][n4+1][kr]=h3;
    split3(vv.z, h1, h2, h3); tl[0][n4+2][kr]=h1; tl[1][n4+2][kr]=h2; tl[2][n4+2][kr]=h3;
    split3(vv.w, h1, h2, h3); tl[0][n4+3][kr]=h1; tl[1][n4+3][kr]=h2; tl[2][n4+3][kr]=h3;
  }
  __syncthreads();
  #pragma unroll
  for (int i = 0; i < 4; ++i) {
    const int q = tid + i * 256, nr = q >> 4, k4 = (q & 15) * 4;
    #pragma unroll
    for (int p = 0; p < 3; ++p) {
      const unsigned lo = (unsigned)tl[p][nr][k4]     | ((unsigned)tl[p][nr][k4+1] << 16);
      const unsigned hi = (unsigned)tl[p][nr][k4 + 2] | ((unsigned)tl[p][nr][k4+3] << 16);
      *(uint2*)(dstb + (size_t)p * PS + (size_t)(n0 + nr) * dstK + k0 + k4) = make_uint2(lo, hi);
    }
  }
}

// ---------------------------------------------------------------------------
// Persistent MFMA wavefront scan. Unit = 64x64 out x 64-K. bf16x3 split,
// 6 MFMA passes (a1b1,a1b2,a2b1,a1b3,a2b2,a3b1) -> fp32-equivalent precision.
// LDS: [3 planes][64 rows][8 slots of 8 bf16], slot ^= (row&7) (conflict-free
// b128 frag reads). Unit order per m: cb-major, (src,kc | x,kc) inner so
// register acc carries across all contributions of one dst tile.
// ---------------------------------------------------------------------------
__global__ __launch_bounds__(256, 3) void rnn_scan_k(
    const float* __restrict__ x,
    const ushort_t* __restrict__ wTh,  // [10][3][1024][1024]
    const ushort_t* __restrict__ wTx,  // [4][3][1024][128]
    const ushort_t* __restrict__ wTp,  // [4][3][128][1024]
    const float* __restrict__ cvec,    // [4][H]
    float* __restrict__ zring,         // [5][L][B][H] fp32
    float* __restrict__ outp,          // [B][T][OD]
    int* __restrict__ bar, int nblk)
{
  __shared__ __align__(16) ushort_t s_a[3 * 64 * 64];
  __shared__ __align__(16) ushort_t s_b[3 * 64 * 64];
  const int tid = threadIdx.x, bid = blockIdx.x;
  const int lane = tid & 63, wid = tid >> 6;
  const int qr = wid >> 1, qc = wid & 1;        // wave's 32x32 quadrant
  const int l15 = lane & 15, l4 = lane >> 4;
  const int arow0 = tid & 63, akq = tid >> 6;   // A staging: row, k-quarter
  const int bcol = tid >> 2, bks = tid & 3;     // B staging: col, k-seg
  const int u0 = (UNITS * bid) / nblk;
  const int u1 = (UNITS * (bid + 1)) / nblk;
  const int gb[4] = {0, 0, 1, 3};

  // fragment rows/cols (fixed per thread)
  const int ar0 = qr * 32 + l15, ar1 = ar0 + 16;
  const int bc0 = qc * 32 + l15, bc1 = bc0 + 16;
  const int oa0b = ar0 * 64, oa1b = ar1 * 64, ob0b = bc0 * 64, ob1b = bc1 * 64;
  const int as0 = ar0 & 7, as1 = ar1 & 7, bs0 = bc0 & 7, bs1 = bc1 & 7;

  int* root = bar + 1024;
  int* gen  = bar + 1056;

  for (int v = 0; v < TD + LD; ++v) {
    // zero the slot that becomes the write target at step v+1 (dead now)
    {
      float* zp = zring + (size_t)((v + 1) % NSLOT) * LBH;
      for (int i = bid * 256 + tid; i < LBH; i += nblk * 256)
        __hip_atomic_store(&zp[i], 0.f, __ATOMIC_RELAXED, __HIP_MEMORY_SCOPE_AGENT);
    }

    f32x4 c00 = {0.f,0.f,0.f,0.f}, c01 = c00, c10 = c00, c11 = c00;
    float* cur = nullptr;
    int cldd = 0;

    auto flush = [&]() {
      const int colb = qc * 32 + l15;
      const int rowb = qr * 32 + l4 * 4;
      #pragma unroll
      for (int r = 0; r < 4; ++r) {
        atomicAdd(cur + (size_t)(rowb + r) * cldd + colb,           c00[r]);
        atomicAdd(cur + (size_t)(rowb + r) * cldd + colb + 16,      c01[r]);
        atomicAdd(cur + (size_t)(rowb + 16 + r) * cldd + colb,      c10[r]);
        atomicAdd(cur + (size_t)(rowb + 16 + r) * cldd + colb + 16, c11[r]);
      }
      c00 = f32x4{0.f,0.f,0.f,0.f}; c01 = c00; c10 = c00; c11 = c00;
    };

    for (int u = u0; u < u1; ++u) {
      // ---- decode (block-uniform) ----
      const float* Ab = nullptr; const float* cvp = nullptr;
      const ushort_t* Wt = nullptr;
      float* dst = nullptr;
      int Ars = 0, WK = 0, dstrs = 0; size_t WPS = 0;
      float scale = 1.f;

      if (u < 2688) {
        int m, rel;
        if (u < 288)       { m = 0; rel = u; }
        else if (u < 832)  { m = 1; rel = u - 288; }
        else if (u < 1632) { m = 2; rel = u - 832; }
        else               { m = 3; rel = u - 1632; }
        const int per = (m + 1) * 16 + 2;
        const int cb = rel / per, r2 = rel - cb * per;
        const int t = v - m;
        if (t >= 0 && t < TD) {
          if (r2 < (m + 1) * 16) {
            const int src = r2 >> 4, kc = r2 & 15;
            if (src < m) {                       // G source: h_src^t
              const int j = src;
              Ab  = zring + (size_t)((t + j) % NSLOT) * LBH + (size_t)j * BH + kc * 64;
              cvp = cvec + j * HD + kc * 64;
              scale = (float)(1 << (m - 1 - j));
              Wt = wTh + (size_t)(gb[m] + j) * 3 * HH + (size_t)(cb * 64) * 1024 + kc * 64;
              Ars = HD; WPS = HH; WK = 1024;
              dst = zring + (size_t)(v % NSLOT) * LBH + (size_t)m * BH + cb * 64;
              dstrs = HD;
            } else if (t >= 1) {                 // B source: h_m^{t-1}
              Ab  = zring + (size_t)((v - 1) % NSLOT) * LBH + (size_t)m * BH + kc * 64;
              cvp = cvec + m * HD + kc * 64;
              scale = 1.f;
              Wt = wTh + (size_t)(6 + m) * 3 * HH + (size_t)(cb * 64) * 1024 + kc * 64;
              Ars = HD; WPS = HH; WK = 1024;
              dst = zring + (size_t)(v % NSLOT) * LBH + (size_t)m * BH + cb * 64;
              dstrs = HD;
            }
          } else {                               // x source (K=128, 2 chunks)
            const int xk = r2 - (m + 1) * 16;
            Ab = x + (size_t)t * IND + xk * 64;
            Ars = TD * IND; cvp = nullptr;
            scale = (float)(1 << m);
            Wt = wTx + (size_t)m * 3 * 131072 + (size_t)(cb * 64) * 128 + xk * 64;
            WPS = 131072; WK = 128;
            dst = zring + (size_t)(v % NSLOT) * LBH + (size_t)m * BH + cb * 64;
            dstrs = HD;
          }
        }
      } else {                                   // out projection of h_j^{v-1-j}
        const int r = u - 2688, j = r >> 5, rr = r & 31, ct = rr >> 4, kc = rr & 15;
        const int tp = v - 1 - j;
        if (tp >= 0 && tp < TD) {
          Ab  = zring + (size_t)((v - 1) % NSLOT) * LBH + (size_t)j * BH + kc * 64;
          Ars = HD;
          cvp = cvec + j * HD + kc * 64;
          scale = (float)(1 << (3 - j));
          Wt = wTp + (size_t)j * 3 * 131072 + (size_t)(ct * 64) * 1024 + kc * 64;
          WPS = 131072; WK = 1024;
          dst = outp + (size_t)tp * OD + ct * 64;
          dstrs = TD * OD;
        }
      }
      if (!Ab || !Wt) continue;                  // inactive unit (uniform)

      if (dst != cur) {
        if (cur) flush();
        cur = dst; cldd = dstrs;
      }

      // ---- stage A (relu+bias+scale, split3 -> 3 bf16 LDS planes) ----
      {
        const int swz = arow0 & 7;
        #pragma unroll
        for (int j = 0; j < 4; ++j) {
          const int k4 = akq * 16 + j * 4;
          float4 vv = *(const float4*)(Ab + (size_t)arow0 * Ars + k4);
          if (cvp) {
            const float4 c4 = *(const float4*)(cvp + k4);
            vv.x = fmaxf(vv.x + c4.x, 0.f);
            vv.y = fmaxf(vv.y + c4.y, 0.f);
            vv.z = fmaxf(vv.z + c4.z, 0.f);
            vv.w = fmaxf(vv.w + c4.w, 0.f);
          }
          vv.x *= scale; vv.y *= scale; vv.z *= scale; vv.w *= scale;
          ushort_t x1,x2,x3, y1,y2,y3, z1,z2,z3, w1,w2,w3;
          split3(vv.x, x1,x2,x3); split3(vv.y, y1,y2,y3);
          split3(vv.z, z1,z2,z3); split3(vv.w, w1,w2,w3);
          const int slot = k4 >> 3, half = (k4 >> 2) & 1;
          const int off = arow0 * 64 + 8 * (slot ^ swz) + half * 4;
          *(uint2*)(s_a + off)        = make_uint2((unsigned)x1 | ((unsigned)y1 << 16),
                                                   (unsigned)z1 | ((unsigned)w1 << 16));
          *(uint2*)(s_a + 4096 + off) = make_uint2((unsigned)x2 | ((unsigned)y2 << 16),
                                                   (unsigned)z2 | ((unsigned)w2 << 16));
          *(uint2*)(s_a + 8192 + off) = make_uint2((unsigned)x3 | ((unsigned)y3 << 16),
                                                   (unsigned)z3 | ((unsigned)w3 << 16));
        }
      }
      // ---- stage B (pre-split transposed bf16 planes, straight copy) ----
      {
        const int csw = bcol & 7;
        #pragma unroll
        for (int p = 0; p < 3; ++p) {
          const ushort_t* wp = Wt + (size_t)p * WPS + (size_t)bcol * WK;
          const uint4 f0 = *(const uint4*)(wp + bks * 8);
          const uint4 f1 = *(const uint4*)(wp + 32 + bks * 8);
          ushort_t* bb = s_b + p * 4096 + bcol * 64;
          *(uint4*)(bb + 8 * (bks ^ csw))       = f0;
          *(uint4*)(bb + 8 * ((bks + 4) ^ csw)) = f1;
        }
      }
      __syncthreads();

      // ---- inner: 2 K-steps of 32; 24 MFMA 16x16x32 per k-step per wave ----
      #pragma unroll
      for (int s = 0; s < 2; ++s) {
        const int sl = s * 4 + l4;
        const int oa0 = oa0b + 8 * (sl ^ as0);
        const int oa1 = oa1b + 8 * (sl ^ as1);
        const int ob0 = ob0b + 8 * (sl ^ bs0);
        const int ob1 = ob1b + 8 * (sl ^ bs1);
        const short8x A01 = *(const short8x*)(s_a + oa0);
        const short8x A02 = *(const short8x*)(s_a + 4096 + oa0);
        const short8x A03 = *(const short8x*)(s_a + 8192 + oa0);
        const short8x A11 = *(const short8x*)(s_a + oa1);
        const short8x A12 = *(const short8x*)(s_a + 4096 + oa1);
        const short8x A13 = *(const short8x*)(s_a + 8192 + oa1);
        const short8x B01 = *(const short8x*)(s_b + ob0);
        const short8x B02 = *(const short8x*)(s_b + 4096 + ob0);
        const short8x B03 = *(const short8x*)(s_b + 8192 + ob0);
        const short8x B11 = *(const short8x*)(s_b + ob1);
        const short8x B12 = *(const short8x*)(s_b + 4096 + ob1);
        const short8x B13 = *(const short8x*)(s_b + 8192 + ob1);
        c00 = __builtin_amdgcn_mfma_f32_16x16x32_bf16(A01, B01, c00, 0, 0, 0);
        c00 = __builtin_amdgcn_mfma_f32_16x16x32_bf16(A01, B02, c00, 0, 0, 0);
        c00 = __builtin_amdgcn_mfma_f32_16x16x32_bf16(A02, B01, c00, 0, 0, 0);
        c00 = __builtin_amdgcn_mfma_f32_16x16x32_bf16(A01, B03, c00, 0, 0, 0);
        c00 = __builtin_amdgcn_mfma_f32_16x16x32_bf16(A02, B02, c00, 0, 0, 0);
        c00 = __builtin_amdgcn_mfma_f32_16x16x32_bf16(A03, B01, c00, 0, 0, 0);
        c01 = __builtin_amdgcn_mfma_f32_16x16x32_bf16(A01, B11, c01, 0, 0, 0);
        c01 = __builtin_amdgcn_mfma_f32_16x16x32_bf16(A01, B12, c01, 0, 0, 0);
        c01 = __builtin_amdgcn_mfma_f32_16x16x32_bf16(A02, B11, c01, 0, 0, 0);
        c01 = __builtin_amdgcn_mfma_f32_16x16x32_bf16(A01, B13, c01, 0, 0, 0);
        c01 = __builtin_amdgcn_mfma_f32_16x16x32_bf16(A02, B12, c01, 0, 0, 0);
        c01 = __builtin_amdgcn_mfma_f32_16x16x32_bf16(A03, B11, c01, 0, 0, 0);
        c10 = __builtin_amdgcn_mfma_f32_16x16x32_bf16(A11, B01, c10, 0, 0, 0);
        c10 = __builtin_amdgcn_mfma_f32_16x16x32_bf16(A11, B02, c10, 0, 0, 0);
        c10 = __builtin_amdgcn_mfma_f32_16x16x32_bf16(A12, B01, c10, 0, 0, 0);
        c10 = __builtin_amdgcn_mfma_f32_16x16x32_bf16(A11, B03, c10, 0, 0, 0);
        c10 = __builtin_amdgcn_mfma_f32_16x16x32_bf16(A12, B02, c10, 0, 0, 0);
        c10 = __builtin_amdgcn_mfma_f32_16x16x32_bf16(A13, B01, c10, 0, 0, 0);
        c11 = __builtin_amdgcn_mfma_f32_16x16x32_bf16(A11, B11, c11, 0, 0, 0);
        c11 = __builtin_amdgcn_mfma_f32_16x16x32_bf16(A11, B12, c11, 0, 0, 0);
        c11 = __builtin_amdgcn_mfma_f32_16x16x32_bf16(A12, B11, c11, 0, 0, 0);
        c11 = __builtin_amdgcn_mfma_f32_16x16x32_bf16(A11, B13, c11, 0, 0, 0);
        c11 = __builtin_amdgcn_mfma_f32_16x16x32_bf16(A12, B12, c11, 0, 0, 0);
        c11 = __builtin_amdgcn_mfma_f32_16x16x32_bf16(A13, B11, c11, 0, 0, 0);
      }
      __syncthreads();
    }

    if (cur) flush();

    // ---- grid barrier: 32-leaf tree, monotonic counters ----
    __syncthreads();
    if (tid == 0) {
      int* leaf = bar + (bid & 31) * 32;
      const int lc = nblk >> 5;
      const int p = __hip_atomic_fetch_add(leaf, 1, __ATOMIC_ACQ_REL, __HIP_MEMORY_SCOPE_AGENT);
      if (p == (v + 1) * lc - 1) {
        const int q = __hip_atomic_fetch_add(root, 1, __ATOMIC_ACQ_REL, __HIP_MEMORY_SCOPE_AGENT);
        if (q == (v + 1) * 32 - 1) {
          __hip_atomic_store(gen, v + 1, __ATOMIC_RELEASE, __HIP_MEMORY_SCOPE_AGENT);
        } else {
          while (__hip_atomic_load(gen, __ATOMIC_RELAXED, __HIP_MEMORY_SCOPE_AGENT) < v + 1)
            __builtin_amdgcn_s_sleep(2);
          __builtin_amdgcn_fence(__ATOMIC_ACQUIRE, "agent");
        }
      } else {
        while (__hip_atomic_load(gen, __ATOMIC_RELAXED, __HIP_MEMORY_SCOPE_AGENT) < v + 1)
          __builtin_amdgcn_s_sleep(2);
        __builtin_amdgcn_fence(__ATOMIC_ACQUIRE, "agent");
      }
    }
    __syncthreads();
  }
}

// ---------------------------------------------------------------------------
extern "C" void kernel_launch(void* const* d_in, const int* in_sizes, int n_in,
                              void* d_out, int out_size, void* d_ws, size_t ws_size,
                              hipStream_t stream)
{
  (void)in_sizes; (void)n_in; (void)out_size; (void)ws_size;

  const float* x        = (const float*)d_in[0];
  const float* Wi       = (const float*)d_in[1];
  const float* bi       = (const float*)d_in[2];
  const float* Wh       = (const float*)d_in[3];
  const float* bh_dense = (const float*)d_in[4];
  const float* bh       = (const float*)d_in[5];
  const float* Wy       = (const float*)d_in[6];
  const float* by_dense = (const float*)d_in[7];
  const float* by       = (const float*)d_in[8];
  const float* Wo       = (const float*)d_in[9];
  const float* bo_dense = (const float*)d_in[10];
  const float* o_bias   = (const float*)d_in[11];
  float* out = (float*)d_out;
  float* ws  = (float*)d_ws;

  size_t off = 0;
  float* G       = ws + off; off += (size_t)6 * HH;          // 24 MB
  float* WiA     = ws + off; off += (size_t)4 * IND * HD;
  float* P       = ws + off; off += (size_t)4 * HD * OD;
  float* WiWo    = ws + off; off += (size_t)IND * OD;
  float* cvec    = ws + off; off += (size_t)4 * HD;
  float* const_o = ws + off; off += OD;
  off = (off + 63) & ~(size_t)63;
  float* zring   = ws + off; off += (size_t)NSLOT * LBH;     // 5.25 MB
  int*   bar     = (int*)(ws + off); off += 4096;            // 16 KB barrier
  ushort_t* wTh  = (ushort_t*)(ws + off); off += (size_t)10 * 3 * HH / 2;      // 60 MB
  ushort_t* wTx  = (ushort_t*)(ws + off); off += (size_t)4 * 3 * 131072 / 2;   // 3 MB
  ushort_t* wTp  = (ushort_t*)(ws + off); off += (size_t)4 * 3 * 131072 / 2;   // 3 MB

  // co-residency: 48KB LDS/block -> up to 3 blocks/CU; trust occupancy API.
  int occ = 2;
  if (hipOccupancyMaxActiveBlocksPerMultiprocessor(&occ, rnn_scan_k, 256, 0) != hipSuccess)
    occ = 2;
  if (occ < 1) occ = 1;
  if (occ > 3) occ = 3;
  const int nblk = 256 * occ;

  hipMemsetAsync(zring, 0, (size_t)NSLOT * LBH * sizeof(float) + 16384, stream);

  consts_k<<<17, 256, 0, stream>>>(Wh, bh_dense, bh, by_dense, by, bi,
                                   Wo, bo_dense, o_bias, cvec, const_o);
  prep1_k<<<898, 256, 0, stream>>>(Wy, Wh, Wi, Wo, G, WiA, P, WiWo);
  prep2_k<<<512, 256, 0, stream>>>(x, WiWo, const_o, out);
  prep3_k<<<2816, 256, 0, stream>>>(G, Wh, WiA, P, wTh, wTx, wTp);
  rnn_scan_k<<<nblk, 256, 0, stream>>>(x, wTh, wTx, wTp, cvec, zring, out, bar, nblk);
}

// Round 5
// 18038.103 us; speedup vs baseline: 3.5770x; 1.1176x over previous
//
#include <hip/hip_runtime.h>
#include <cstdint>
#include <cstddef>

namespace {
constexpr int HD  = 1024;
constexpr int LD  = 4;
constexpr int BD  = 64;
constexpr int TD  = 512;
constexpr int IND = 128;
constexpr int OD  = 128;
constexpr int NSLOT = 5;
constexpr int LBH = LD * BD * HD;   // 262144
constexpr int BH  = BD * HD;        // 65536
constexpr int UNITS = 2816;         // h/x: 2688, out: 128
constexpr size_t HH = (size_t)HD * HD;
constexpr int BLOB_US = 12288;      // ushorts per 24KB blob (3 planes x 64 x 64)
}

typedef unsigned short ushort_t;
typedef __attribute__((ext_vector_type(8))) short short8x;
typedef __attribute__((ext_vector_type(4))) float f32x4;

__device__ __forceinline__ ushort_t f2bf_rne(float f) {
  unsigned u = __builtin_bit_cast(unsigned, f);
  u += 0x7FFFu + ((u >> 16) & 1u);
  return (ushort_t)(u >> 16);
}
// Dekker-style truncation split: exact residuals, ~10 VALU.
__device__ __forceinline__ void split3(float f, ushort_t& h1, ushort_t& h2, ushort_t& h3) {
  const unsigned u = __builtin_bit_cast(unsigned, f);
  h1 = (ushort_t)(u >> 16);
  const float r = f - __builtin_bit_cast(float, u & 0xFFFF0000u);   // exact
  const unsigned u2 = __builtin_bit_cast(unsigned, r);
  h2 = (ushort_t)(u2 >> 16);
  const float r2 = r - __builtin_bit_cast(float, u2 & 0xFFFF0000u); // exact
  h3 = f2bf_rne(r2);
}

// ---------------------------------------------------------------------------
// Canonical unit enumeration (shared by prep3 and scan):
//   u < 2688: h/x-path. m prefix sizes {288,544,800,1056}; per=(m+1)*16+2;
//             cb=rel/per (16 col-tiles), r2=rel%per;
//             r2<(m+1)*16: src=r2>>4, kc=r2&15  (src<m: G, src==m: B)
//             else: xk=r2-(m+1)*16 in {0,1}  (x-path)
//   else:     out-path. r=u-2688; j=r>>5; ct=(r&31)>>4; kc=r&15.
// ---------------------------------------------------------------------------
struct WSrc { const float* base; int ld; int k0; int n0; };
__device__ __forceinline__ WSrc unit_wsrc(
    int u, const float* G, const float* Wh, const float* WiA, const float* P)
{
  const int gb[4] = {0, 0, 1, 3};
  WSrc w;
  if (u < 2688) {
    int m, rel;
    if (u < 288)       { m = 0; rel = u; }
    else if (u < 832)  { m = 1; rel = u - 288; }
    else if (u < 1632) { m = 2; rel = u - 832; }
    else               { m = 3; rel = u - 1632; }
    const int per = (m + 1) * 16 + 2;
    const int cb = rel / per, r2 = rel - cb * per;
    if (r2 < (m + 1) * 16) {
      const int src = r2 >> 4, kc = r2 & 15;
      if (src < m) w.base = G + (size_t)(gb[m] + src) * HH;
      else         w.base = Wh + (size_t)m * 2 * HH + HH;
      w.ld = HD; w.k0 = kc * 64; w.n0 = cb * 64;
    } else {
      const int xk = r2 - (m + 1) * 16;
      w.base = WiA + (size_t)m * IND * HD;
      w.ld = HD; w.k0 = xk * 64; w.n0 = cb * 64;
    }
  } else {
    const int r = u - 2688, j = r >> 5, rr = r & 31, ct = rr >> 4, kc = rr & 15;
    w.base = P + (size_t)j * HD * OD;
    w.ld = OD; w.k0 = kc * 64; w.n0 = ct * 64;
  }
  return w;
}

// ---------------------------------------------------------------------------
// fp32 GEMM tile (64x128, 256 thr) for prep kernels (proven).
// ---------------------------------------------------------------------------
__device__ __forceinline__ void gemm_tile(
    const float* __restrict__ A, int lda, const float* __restrict__ Bm, int ldb,
    float* __restrict__ C, int ldc, int K, int row0, int col0,
    float alpha, const float* __restrict__ addvec)
{
  __shared__ float a_lds[64][65];
  __shared__ __align__(16) float b_lds[64][132];
  const int tid = threadIdx.x;
  const int rg = tid >> 4, cg = tid & 15;

  float acc[4][8];
  #pragma unroll
  for (int i = 0; i < 4; ++i)
    #pragma unroll
    for (int j = 0; j < 8; ++j) acc[i][j] = 0.f;

  for (int k0 = 0; k0 < K; k0 += 64) {
    #pragma unroll
    for (int i = 0; i < 4; ++i) {
      const int q = tid + i * 256;
      const int r = q >> 4;
      const int k4 = (q & 15) << 2;
      const float4 v = *(const float4*)(A + (size_t)(row0 + r) * lda + k0 + k4);
      a_lds[r][k4 + 0] = v.x; a_lds[r][k4 + 1] = v.y;
      a_lds[r][k4 + 2] = v.z; a_lds[r][k4 + 3] = v.w;
    }
    #pragma unroll
    for (int i = 0; i < 8; ++i) {
      const int q = tid + i * 256;
      const int k = q >> 5;
      const int c4 = (q & 31) << 2;
      *(float4*)&b_lds[k][c4] = *(const float4*)(Bm + (size_t)(k0 + k) * ldb + col0 + c4);
    }
    __syncthreads();
    #pragma unroll 4
    for (int k = 0; k < 64; ++k) {
      float wv[8], av[4];
      *(float4*)&wv[0] = *(const float4*)&b_lds[k][cg * 8];
      *(float4*)&wv[4] = *(const float4*)&b_lds[k][cg * 8 + 4];
      #pragma unroll
      for (int i = 0; i < 4; ++i) av[i] = a_lds[rg * 4 + i][k];
      #pragma unroll
      for (int i = 0; i < 4; ++i)
        #pragma unroll
        for (int j = 0; j < 8; ++j)
          acc[i][j] = fmaf(av[i], wv[j], acc[i][j]);
    }
    __syncthreads();
  }

  #pragma unroll
  for (int i = 0; i < 4; ++i) {
    const int r = row0 + rg * 4 + i;
    #pragma unroll
    for (int j = 0; j < 8; ++j) {
      const int c = col0 + cg * 8 + j;
      float v = alpha * acc[i][j];
      if (addvec) v += addvec[c];
      C[(size_t)r * ldc + c] = v;
    }
  }
}

__global__ __launch_bounds__(256) void prep1_k(
    const float* __restrict__ Wy, const float* __restrict__ Wh,
    const float* __restrict__ Wi, const float* __restrict__ Wo,
    float* __restrict__ G, float* __restrict__ WiA,
    float* __restrict__ P, float* __restrict__ WiWo)
{
  static const int pj[6] = {0, 0, 1, 0, 1, 2};
  static const int pm[6] = {1, 2, 2, 3, 3, 3};
  const int bid = blockIdx.x;
  const float *A, *Bm; float* C; int lda, ldb, ldc, row0, col0;
  if (bid < 768) {
    const int p = bid >> 7, rr = bid & 127;
    A = Wy + (size_t)pj[p] * HH; lda = HD;
    Bm = Wh + (size_t)pm[p] * 2 * HH; ldb = HD;
    C = G + (size_t)p * HH; ldc = HD;
    row0 = (rr >> 3) * 64; col0 = (rr & 7) * 128;
  } else if (bid < 832) {
    const int r = bid - 768, m = r >> 4;
    A = Wi; lda = HD;
    Bm = Wh + (size_t)m * 2 * HH; ldb = HD;
    C = WiA + (size_t)m * IND * HD; ldc = HD;
    row0 = ((r >> 3) & 1) * 64; col0 = (r & 7) * 128;
  } else if (bid < 896) {
    const int r = bid - 832, j = r >> 4;
    A = Wy + (size_t)j * HH; lda = HD;
    Bm = Wo; ldb = OD;
    C = P + (size_t)j * HD * OD; ldc = OD;
    row0 = (r & 15) * 64; col0 = 0;
  } else {
    const int r = bid - 896;
    A = Wi; lda = HD; Bm = Wo; ldb = OD; C = WiWo; ldc = OD;
    row0 = r * 64; col0 = 0;
  }
  gemm_tile(A, lda, Bm, ldb, C, ldc, HD, row0, col0, 1.f, nullptr);
}

__global__ __launch_bounds__(256) void prep2_k(
    const float* __restrict__ x, const float* __restrict__ WiWo,
    const float* __restrict__ const_o, float* __restrict__ out)
{
  gemm_tile(x, IND, WiWo, OD, out, OD, IND, blockIdx.x * 64, 0, 16.f, const_o);
}

__global__ __launch_bounds__(256) void consts_k(
    const float* __restrict__ Wh, const float* __restrict__ bh_dense, const float* __restrict__ bh,
    const float* __restrict__ by_dense, const float* __restrict__ by, const float* __restrict__ bi,
    const float* __restrict__ Wo, const float* __restrict__ bo_dense, const float* __restrict__ o_bias,
    float* __restrict__ cvec, float* __restrict__ const_o)
{
  __shared__ float e_lds[HD];
  const int tid = threadIdx.x;
  if (blockIdx.x < 16) {
    const int m = blockIdx.x >> 2;
    const int hcol = ((blockIdx.x & 3) << 8) + tid;
    for (int k = tid; k < HD; k += 256) {
      float e = (float)(1 << m) * bi[k];
      for (int j = 0; j < m; ++j)
        e += (float)(1 << (m - 1 - j)) * (by_dense[j * HD + k] + by[j * HD + k]);
      e_lds[k] = e;
    }
    __syncthreads();
    float acc = bh_dense[m * HD + hcol] + bh[m * HD + hcol];
    for (int k = 0; k < HD; ++k)
      acc = fmaf(e_lds[k], Wh[(size_t)m * 2 * HH + (size_t)k * HD + hcol], acc);
    cvec[m * HD + hcol] = acc;
  } else {
    if (tid < OD) {
      float acc = bo_dense[tid] + o_bias[tid];
      for (int k = 0; k < HD; ++k) {
        float e = 16.f * bi[k];
        e += 8.f * (by_dense[0 * HD + k] + by[0 * HD + k]);
        e += 4.f * (by_dense[1 * HD + k] + by[1 * HD + k]);
        e += 2.f * (by_dense[2 * HD + k] + by[2 * HD + k]);
        e += 1.f * (by_dense[3 * HD + k] + by[3 * HD + k]);
        acc = fmaf(e, Wo[(size_t)k * OD + tid], acc);
      }
      const_o[tid] = acc;
    }
  }
}

// ---------------------------------------------------------------------------
// prep3: one block per unit (2816). Emits the unit's weight tile as a 24KB
// blob that is the EXACT LDS image the scan needs:
//   blob[p*4096 + c*64 + 8*(s8^(c&7)) + e] = plane_p( W[k0+s8*8+e][n0+c] )
// ---------------------------------------------------------------------------
__global__ __launch_bounds__(256) void prep3_k(
    const float* __restrict__ G, const float* __restrict__ Wh,
    const float* __restrict__ WiA, const float* __restrict__ P,
    ushort_t* __restrict__ blobs)
{
  __shared__ ushort_t tl[3][64][66];
  const int tid = threadIdx.x;
  const int u = blockIdx.x;
  const WSrc w = unit_wsrc(u, G, Wh, WiA, P);

  #pragma unroll
  for (int i = 0; i < 4; ++i) {
    const int q = tid + i * 256;
    const int kr = q >> 4, n4 = (q & 15) * 4;
    const float4 vv = *(const float4*)(w.base + (size_t)(w.k0 + kr) * w.ld + w.n0 + n4);
    ushort_t h1, h2, h3;
    split3(vv.x, h1, h2, h3); tl[0][n4+0][kr]=h1; tl[1][n4+0][kr]=h2; tl[2][n4+0][kr]=h3;
    split3(vv.y, h1, h2, h3); tl[0][n4+1][kr]=h1; tl[1][n4+1][kr]=h2; tl[2][n4+1][kr]=h3;
    split3(vv.z, h1, h2, h3); tl[0][n4+2][kr]=h1; tl[1][n4+2][kr]=h2; tl[2][n4+2][kr]=h3;
    split3(vv.w, h1, h2, h3); tl[0][n4+3][kr]=h1; tl[1][n4+3][kr]=h2; tl[2][n4+3][kr]=h3;
  }
  __syncthreads();

  ushort_t* ob = blobs + (size_t)u * BLOB_US;
  #pragma unroll
  for (int i = 0; i < 2; ++i) {
    const int idx = tid + i * 256;
    const int c = idx >> 3, s8 = idx & 7;
    #pragma unroll
    for (int p = 0; p < 3; ++p) {
      const ushort_t* t8 = &tl[p][c][s8 * 8];
      const unsigned w0 = (unsigned)t8[0] | ((unsigned)t8[1] << 16);
      const unsigned w1 = (unsigned)t8[2] | ((unsigned)t8[3] << 16);
      const unsigned w2 = (unsigned)t8[4] | ((unsigned)t8[5] << 16);
      const unsigned w3 = (unsigned)t8[6] | ((unsigned)t8[7] << 16);
      *(uint4*)(ob + p * 4096 + c * 64 + 8 * (s8 ^ (c & 7))) = make_uint4(w0, w1, w2, w3);
    }
  }
}

// ---------------------------------------------------------------------------
// Persistent MFMA wavefront scan with async pre-swizzled weight DMA.
// Per unit: [flush?][A-load+split (drains vmcnt incl. current blob)]
//           [DMA next blob -> other buf][lgkm0+barrier][MFMA][lgkm0+barrier]
// No vmcnt(0) drain between units -> weight DMA overlaps compute.
// ---------------------------------------------------------------------------
__device__ __forceinline__ void issue_dma(const ushort_t* g, ushort_t* l, int wid, int lane) {
  const char* gs = (const char*)g + wid * 6144 + lane * 16;
  char* ls = (char*)l + wid * 6144;
  #pragma unroll
  for (int i = 0; i < 6; ++i)
    __builtin_amdgcn_global_load_lds(
        (const __attribute__((address_space(1))) void*)(gs + i * 1024),
        (__attribute__((address_space(3))) void*)(ls + i * 1024), 16, 0, 0);
}

__global__ __launch_bounds__(256, 2) void rnn_scan_k(
    const float* __restrict__ x,
    const ushort_t* __restrict__ blobs,  // [2816][24KB] pre-swizzled
    const float* __restrict__ cvec,      // [4][H]
    float* __restrict__ zring,           // [5][L][B][H] fp32
    float* __restrict__ outp,            // [B][T][OD]
    int* __restrict__ bar, int nblk)
{
  __shared__ __align__(16) ushort_t s_a[3 * 4096];       // 24KB
  __shared__ __align__(16) ushort_t s_b[2 * 3 * 4096];   // 48KB double buffer
  const int tid = threadIdx.x, bid = blockIdx.x;
  const int lane = tid & 63, wid = tid >> 6;
  const int qr = wid >> 1, qc = wid & 1;
  const int l15 = lane & 15, l4 = lane >> 4;
  const int ar_r = tid >> 2, ar_kq = tid & 3;   // A staging: row, k-quarter
  const int u0 = (UNITS * bid) / nblk;
  const int u1 = (UNITS * (bid + 1)) / nblk;
  const int gb[4] = {0, 0, 1, 3};

  const int ar0 = qr * 32 + l15, ar1 = ar0 + 16;
  const int bc0 = qc * 32 + l15, bc1 = bc0 + 16;
  const int oa0b = ar0 * 64, oa1b = ar1 * 64, ob0b = bc0 * 64, ob1b = bc1 * 64;
  const int as0 = ar0 & 7, as1 = ar1 & 7, bs0 = bc0 & 7, bs1 = bc1 & 7;

  int* root = bar + 1024;
  int* gen  = bar + 1056;

  // prologue: DMA first blob into buf0
  issue_dma(blobs + (size_t)u0 * BLOB_US, s_b, wid, lane);
  int pbuf = 0;

  for (int v = 0; v < TD + LD; ++v) {
    // zero the slot that becomes the write target at step v+1 (dead now)
    {
      float* zp = zring + (size_t)((v + 1) % NSLOT) * LBH;
      for (int i = bid * 256 + tid; i < LBH; i += nblk * 256)
        __hip_atomic_store(&zp[i], 0.f, __ATOMIC_RELAXED, __HIP_MEMORY_SCOPE_AGENT);
    }

    f32x4 c00 = {0.f,0.f,0.f,0.f}, c01 = c00, c10 = c00, c11 = c00;
    float* cur = nullptr;
    int cldd = 0;

    auto flush = [&]() {
      const int colb = qc * 32 + l15;
      const int rowb = qr * 32 + l4 * 4;
      #pragma unroll
      for (int r = 0; r < 4; ++r) {
        atomicAdd(cur + (size_t)(rowb + r) * cldd + colb,           c00[r]);
        atomicAdd(cur + (size_t)(rowb + r) * cldd + colb + 16,      c01[r]);
        atomicAdd(cur + (size_t)(rowb + 16 + r) * cldd + colb,      c10[r]);
        atomicAdd(cur + (size_t)(rowb + 16 + r) * cldd + colb + 16, c11[r]);
      }
      c00 = f32x4{0.f,0.f,0.f,0.f}; c01 = c00; c10 = c00; c11 = c00;
    };

    for (int u = u0; u < u1; ++u) {
      // ---- decode (block-uniform) ----
      const float* Ab = nullptr; const float* cvp = nullptr;
      float* dst = nullptr;
      int Ars = 0, dstrs = 0;
      float scale = 1.f;

      if (u < 2688) {
        int m, rel;
        if (u < 288)       { m = 0; rel = u; }
        else if (u < 832)  { m = 1; rel = u - 288; }
        else if (u < 1632) { m = 2; rel = u - 832; }
        else               { m = 3; rel = u - 1632; }
        const int per = (m + 1) * 16 + 2;
        const int cb = rel / per, r2 = rel - cb * per;
        const int t = v - m;
        if (t >= 0 && t < TD) {
          if (r2 < (m + 1) * 16) {
            const int src = r2 >> 4, kc = r2 & 15;
            if (src < m) {                       // G source: h_src^t
              const int j = src;
              Ab  = zring + (size_t)((t + j) % NSLOT) * LBH + (size_t)j * BH + kc * 64;
              cvp = cvec + j * HD + kc * 64;
              scale = (float)(1 << (m - 1 - j));
              Ars = HD;
              dst = zring + (size_t)(v % NSLOT) * LBH + (size_t)m * BH + cb * 64;
              dstrs = HD;
            } else if (t >= 1) {                 // B source: h_m^{t-1}
              Ab  = zring + (size_t)((v - 1) % NSLOT) * LBH + (size_t)m * BH + kc * 64;
              cvp = cvec + m * HD + kc * 64;
              scale = 1.f;
              Ars = HD;
              dst = zring + (size_t)(v % NSLOT) * LBH + (size_t)m * BH + cb * 64;
              dstrs = HD;
            }
          } else {                               // x source
            const int xk = r2 - (m + 1) * 16;
            Ab = x + (size_t)t * IND + xk * 64;
            Ars = TD * IND; cvp = nullptr;
            scale = (float)(1 << m);
            dst = zring + (size_t)(v % NSLOT) * LBH + (size_t)m * BH + cb * 64;
            dstrs = HD;
          }
        }
      } else {                                   // out projection of h_j^{v-1-j}
        const int r = u - 2688, j = r >> 5, rr = r & 31, ct = rr >> 4, kc = rr & 15;
        const int tp = v - 1 - j;
        if (tp >= 0 && tp < TD) {
          Ab  = zring + (size_t)((v - 1) % NSLOT) * LBH + (size_t)j * BH + kc * 64;
          Ars = HD;
          cvp = cvec + j * HD + kc * 64;
          scale = (float)(1 << (3 - j));
          dst = outp + (size_t)tp * OD + ct * 64;
          dstrs = TD * OD;
        }
      }
      const bool active = (Ab != nullptr);

      if (active && dst != cur) {
        if (cur) flush();
        cur = dst; cldd = dstrs;
      }

      // ---- stage A: conflict-free 16B stores; consuming A drains vmcnt,
      //      which also guarantees this unit's blob (DMA'd last unit) landed.
      if (active) {
        float vv[16];
        const float* ap = Ab + (size_t)ar_r * (size_t)Ars + ar_kq * 16;
        *(float4*)&vv[0]  = *(const float4*)(ap + 0);
        *(float4*)&vv[4]  = *(const float4*)(ap + 4);
        *(float4*)&vv[8]  = *(const float4*)(ap + 8);
        *(float4*)&vv[12] = *(const float4*)(ap + 12);
        if (cvp) {
          const float* cp2 = cvp + ar_kq * 16;
          #pragma unroll
          for (int e = 0; e < 16; ++e) vv[e] = fmaxf(vv[e] + cp2[e], 0.f);
        }
        #pragma unroll
        for (int e = 0; e < 16; ++e) vv[e] *= scale;
        #pragma unroll
        for (int i = 0; i < 2; ++i) {
          unsigned p1[4], p2[4], p3[4];
          #pragma unroll
          for (int q2 = 0; q2 < 4; ++q2) {
            ushort_t a1, a2, a3, b1, b2, b3;
            split3(vv[i * 8 + q2 * 2],     a1, a2, a3);
            split3(vv[i * 8 + q2 * 2 + 1], b1, b2, b3);
            p1[q2] = (unsigned)a1 | ((unsigned)b1 << 16);
            p2[q2] = (unsigned)a2 | ((unsigned)b2 << 16);
            p3[q2] = (unsigned)a3 | ((unsigned)b3 << 16);
          }
          const int s8 = ar_kq * 2 + i;
          const int off = ar_r * 64 + 8 * (s8 ^ (ar_r & 7));
          *(uint4*)(s_a + off)        = make_uint4(p1[0], p1[1], p1[2], p1[3]);
          *(uint4*)(s_a + 4096 + off) = make_uint4(p2[0], p2[1], p2[2], p2[3]);
          *(uint4*)(s_a + 8192 + off) = make_uint4(p3[0], p3[1], p3[2], p3[3]);
        }
      }

      // ---- prefetch next blob into the other buffer (stays in flight) ----
      asm volatile("" ::: "memory");   // keep DMA after A-consume/stores
      {
        const int nu = (u + 1 < u1) ? (u + 1) : u0;
        issue_dma(blobs + (size_t)nu * BLOB_US, s_b + (pbuf ^ 1) * BLOB_US, wid, lane);
      }
      asm volatile("s_waitcnt lgkmcnt(0)" ::: "memory");
      __builtin_amdgcn_s_barrier();
      __builtin_amdgcn_sched_barrier(0);

      // ---- MFMA: 2 K32 steps, 24 MFMA each (6-pass bf16x3) ----
      if (active) {
        const ushort_t* sbb = s_b + pbuf * BLOB_US;
        #pragma unroll
        for (int s = 0; s < 2; ++s) {
          const int sl = s * 4 + l4;
          const int oa0 = oa0b + 8 * (sl ^ as0);
          const int oa1 = oa1b + 8 * (sl ^ as1);
          const int ob0 = ob0b + 8 * (sl ^ bs0);
          const int ob1 = ob1b + 8 * (sl ^ bs1);
          const short8x A01 = *(const short8x*)(s_a + oa0);
          const short8x A02 = *(const short8x*)(s_a + 4096 + oa0);
          const short8x A03 = *(const short8x*)(s_a + 8192 + oa0);
          const short8x A11 = *(const short8x*)(s_a + oa1);
          const short8x A12 = *(const short8x*)(s_a + 4096 + oa1);
          const short8x A13 = *(const short8x*)(s_a + 8192 + oa1);
          const short8x B01 = *(const short8x*)(sbb + ob0);
          const short8x B02 = *(const short8x*)(sbb + 4096 + ob0);
          const short8x B03 = *(const short8x*)(sbb + 8192 + ob0);
          const short8x B11 = *(const short8x*)(sbb + ob1);
          const short8x B12 = *(const short8x*)(sbb + 4096 + ob1);
          const short8x B13 = *(const short8x*)(sbb + 8192 + ob1);
          c00 = __builtin_amdgcn_mfma_f32_16x16x32_bf16(A01, B01, c00, 0, 0, 0);
          c00 = __builtin_amdgcn_mfma_f32_16x16x32_bf16(A01, B02, c00, 0, 0, 0);
          c00 = __builtin_amdgcn_mfma_f32_16x16x32_bf16(A02, B01, c00, 0, 0, 0);
          c00 = __builtin_amdgcn_mfma_f32_16x16x32_bf16(A01, B03, c00, 0, 0, 0);
          c00 = __builtin_amdgcn_mfma_f32_16x16x32_bf16(A02, B02, c00, 0, 0, 0);
          c00 = __builtin_amdgcn_mfma_f32_16x16x32_bf16(A03, B01, c00, 0, 0, 0);
          c01 = __builtin_amdgcn_mfma_f32_16x16x32_bf16(A01, B11, c01, 0, 0, 0);
          c01 = __builtin_amdgcn_mfma_f32_16x16x32_bf16(A01, B12, c01, 0, 0, 0);
          c01 = __builtin_amdgcn_mfma_f32_16x16x32_bf16(A02, B11, c01, 0, 0, 0);
          c01 = __builtin_amdgcn_mfma_f32_16x16x32_bf16(A01, B13, c01, 0, 0, 0);
          c01 = __builtin_amdgcn_mfma_f32_16x16x32_bf16(A02, B12, c01, 0, 0, 0);
          c01 = __builtin_amdgcn_mfma_f32_16x16x32_bf16(A03, B11, c01, 0, 0, 0);
          c10 = __builtin_amdgcn_mfma_f32_16x16x32_bf16(A11, B01, c10, 0, 0, 0);
          c10 = __builtin_amdgcn_mfma_f32_16x16x32_bf16(A11, B02, c10, 0, 0, 0);
          c10 = __builtin_amdgcn_mfma_f32_16x16x32_bf16(A12, B01, c10, 0, 0, 0);
          c10 = __builtin_amdgcn_mfma_f32_16x16x32_bf16(A11, B03, c10, 0, 0, 0);
          c10 = __builtin_amdgcn_mfma_f32_16x16x32_bf16(A12, B02, c10, 0, 0, 0);
          c10 = __builtin_amdgcn_mfma_f32_16x16x32_bf16(A13, B01, c10, 0, 0, 0);
          c11 = __builtin_amdgcn_mfma_f32_16x16x32_bf16(A11, B11, c11, 0, 0, 0);
          c11 = __builtin_amdgcn_mfma_f32_16x16x32_bf16(A11, B12, c11, 0, 0, 0);
          c11 = __builtin_amdgcn_mfma_f32_16x16x32_bf16(A12, B11, c11, 0, 0, 0);
          c11 = __builtin_amdgcn_mfma_f32_16x16x32_bf16(A11, B13, c11, 0, 0, 0);
          c11 = __builtin_amdgcn_mfma_f32_16x16x32_bf16(A12, B12, c11, 0, 0, 0);
          c11 = __builtin_amdgcn_mfma_f32_16x16x32_bf16(A13, B11, c11, 0, 0, 0);
        }
      }

      asm volatile("s_waitcnt lgkmcnt(0)" ::: "memory");
      __builtin_amdgcn_s_barrier();
      __builtin_amdgcn_sched_barrier(0);
      pbuf ^= 1;
    }

    if (cur) flush();

    // step end: __syncthreads drains vmcnt (atomics + DMA) for grid visibility
    __syncthreads();
    if (tid == 0) {
      int* leaf = bar + (bid & 31) * 32;
      const int lc = nblk >> 5;
      const int p = __hip_atomic_fetch_add(leaf, 1, __ATOMIC_ACQ_REL, __HIP_MEMORY_SCOPE_AGENT);
      if (p == (v + 1) * lc - 1) {
        const int q = __hip_atomic_fetch_add(root, 1, __ATOMIC_ACQ_REL, __HIP_MEMORY_SCOPE_AGENT);
        if (q == (v + 1) * 32 - 1) {
          __hip_atomic_store(gen, v + 1, __ATOMIC_RELEASE, __HIP_MEMORY_SCOPE_AGENT);
        } else {
          while (__hip_atomic_load(gen, __ATOMIC_RELAXED, __HIP_MEMORY_SCOPE_AGENT) < v + 1)
            __builtin_amdgcn_s_sleep(2);
          __builtin_amdgcn_fence(__ATOMIC_ACQUIRE, "agent");
        }
      } else {
        while (__hip_atomic_load(gen, __ATOMIC_RELAXED, __HIP_MEMORY_SCOPE_AGENT) < v + 1)
          __builtin_amdgcn_s_sleep(2);
        __builtin_amdgcn_fence(__ATOMIC_ACQUIRE, "agent");
      }
    }
    __syncthreads();
  }
}

// ---------------------------------------------------------------------------
extern "C" void kernel_launch(void* const* d_in, const int* in_sizes, int n_in,
                              void* d_out, int out_size, void* d_ws, size_t ws_size,
                              hipStream_t stream)
{
  (void)in_sizes; (void)n_in; (void)out_size; (void)ws_size;

  const float* x        = (const float*)d_in[0];
  const float* Wi       = (const float*)d_in[1];
  const float* bi       = (const float*)d_in[2];
  const float* Wh       = (const float*)d_in[3];
  const float* bh_dense = (const float*)d_in[4];
  const float* bh       = (const float*)d_in[5];
  const float* Wy       = (const float*)d_in[6];
  const float* by_dense = (const float*)d_in[7];
  const float* by       = (const float*)d_in[8];
  const float* Wo       = (const float*)d_in[9];
  const float* bo_dense = (const float*)d_in[10];
  const float* o_bias   = (const float*)d_in[11];
  float* out = (float*)d_out;
  float* ws  = (float*)d_ws;

  size_t off = 0;
  float* G       = ws + off; off += (size_t)6 * HH;          // 24 MB
  float* WiA     = ws + off; off += (size_t)4 * IND * HD;
  float* P       = ws + off; off += (size_t)4 * HD * OD;
  float* WiWo    = ws + off; off += (size_t)IND * OD;
  float* cvec    = ws + off; off += (size_t)4 * HD;
  float* const_o = ws + off; off += OD;
  off = (off + 63) & ~(size_t)63;
  float* zring   = ws + off; off += (size_t)NSLOT * LBH;     // 5.25 MB
  int*   bar     = (int*)(ws + off); off += 4096;            // 16 KB
  off = (off + 15) & ~(size_t)15;
  ushort_t* blobs = (ushort_t*)(ws + off);                   // 2816 x 24KB = 67.6 MB

  // 73.7KB LDS/block -> 2 blocks/CU (147.5 <= 160KB)
  int occ = 2;
  if (hipOccupancyMaxActiveBlocksPerMultiprocessor(&occ, rnn_scan_k, 256, 0) != hipSuccess)
    occ = 2;
  if (occ < 1) occ = 1;
  if (occ > 2) occ = 2;
  const int nblk = 256 * occ;

  hipMemsetAsync(zring, 0, (size_t)NSLOT * LBH * sizeof(float) + 16384, stream);

  consts_k<<<17, 256, 0, stream>>>(Wh, bh_dense, bh, by_dense, by, bi,
                                   Wo, bo_dense, o_bias, cvec, const_o);
  prep1_k<<<898, 256, 0, stream>>>(Wy, Wh, Wi, Wo, G, WiA, P, WiWo);
  prep2_k<<<512, 256, 0, stream>>>(x, WiWo, const_o, out);
  prep3_k<<<UNITS, 256, 0, stream>>>(G, Wh, WiA, P, blobs);
  rnn_scan_k<<<nblk, 256, 0, stream>>>(x, blobs, cvec, zring, out, bar, nblk);
}